// Round 3
// baseline (976.672 us; speedup 1.0000x reference)
//
#include <hip/hip_runtime.h>
#include <hip/hip_bf16.h>

// ---------------------------------------------------------------------------
// WeightOnlyLinear: y = x @ dequant4(qweight, scales, qzeros) + bias
//   x (8192,4096) fp32 | scales (32,12288) | bias (12288) | qweight (512,12288)
//   qzeros (32,1536) | out (8192,12288) fp32
// R3: full m201-style 8-phase 256x256x64 schedule: per-phase
//     {ds_read || 2x global_load_lds -> barrier -> lgkmcnt(0) -> 16 MFMA ->
//      barrier}, counted vmcnt(2) at phases 3/7 only, T1+T2+T5 retained.
// ---------------------------------------------------------------------------

typedef __attribute__((ext_vector_type(8))) short short8;
typedef __attribute__((ext_vector_type(4))) float f32x4;

__device__ __forceinline__ short f2bf(float f) {
  unsigned u = __float_as_uint(f);
  u += 0x7fffu + ((u >> 16) & 1u);
  return (short)(u >> 16);
}

__device__ __forceinline__ void gload_lds16(const void* g, void* l) {
  __builtin_amdgcn_global_load_lds(
      (const __attribute__((address_space(1))) void*)g,
      (__attribute__((address_space(3))) void*)l,
      16, 0, 0);
}

__device__ __forceinline__ void bar() {
  asm volatile("" ::: "memory");
  __builtin_amdgcn_s_barrier();
  asm volatile("" ::: "memory");
}
__device__ __forceinline__ void wait_vm2() {
  asm volatile("s_waitcnt vmcnt(2)" ::: "memory");
}
__device__ __forceinline__ void wait_vm0() {
  asm volatile("s_waitcnt vmcnt(0)" ::: "memory");
}
// barrier -> drain LDS reads -> pin MFMA after this point
__device__ __forceinline__ void phase_sync() {
  asm volatile("" ::: "memory");
  __builtin_amdgcn_s_barrier();
  asm volatile("s_waitcnt lgkmcnt(0)" ::: "memory");
  __builtin_amdgcn_sched_barrier(0);
}

// ---------------------------------------------------------------------------
// Pass 1: dequant + transpose. qweight (K/8, N) int32 -> Wt (N, K) bf16.
// ---------------------------------------------------------------------------
__global__ __launch_bounds__(256) void dequant_kernel(
    const int* __restrict__ qweight, const int* __restrict__ qzeros,
    const float* __restrict__ scales, short* __restrict__ Wt,
    int in_f, int out_f) {
  __shared__ __align__(16) short T[64][72];
  const int n0 = blockIdx.x * 64;
  const int k0 = blockIdx.y * 64;
  const int t = threadIdx.x;
  const int nl = t & 63;
  const int kw = t >> 6;
  const int n = n0 + nl;
  const int g = k0 >> 7;
  const float sc = scales[(size_t)g * out_f + n];
  const int zpw = qzeros[(size_t)g * (out_f >> 3) + (n >> 3)];
  const float zp = (float)(((zpw >> ((n & 7) * 4)) & 15) + 1);
  const float zs = zp * sc;
#pragma unroll
  for (int rr = 0; rr < 2; ++rr) {
    const int kwi = kw + rr * 4;
    const int w = qweight[(size_t)((k0 >> 3) + kwi) * out_f + n];
    short8 v;
#pragma unroll
    for (int e = 0; e < 8; ++e) {
      float f = (float)((w >> (4 * e)) & 15) * sc - zs;
      v[e] = f2bf(f);
    }
    *(short8*)&T[nl][kwi * 8] = v;
  }
  __syncthreads();
#pragma unroll
  for (int rr = 0; rr < 2; ++rr) {
    const int c = rr * 256 + t;
    const int row = c >> 3, ch = c & 7;
    *(short8*)&Wt[(size_t)(n0 + row) * in_f + k0 + ch * 8] =
        *(const short8*)&T[row][ch * 8];
  }
}

// ---------------------------------------------------------------------------
// Pass 2: x fp32 -> bf16.
// ---------------------------------------------------------------------------
__global__ __launch_bounds__(256) void cvt_kernel(
    const float* __restrict__ x, short* __restrict__ xb, long n8) {
  long i = (long)blockIdx.x * blockDim.x + threadIdx.x;
  if (i >= n8) return;
  const float* src = x + i * 8;
  float4 a = *(const float4*)src;
  float4 b = *(const float4*)(src + 4);
  short8 v;
  v[0] = f2bf(a.x); v[1] = f2bf(a.y); v[2] = f2bf(a.z); v[3] = f2bf(a.w);
  v[4] = f2bf(b.x); v[5] = f2bf(b.y); v[6] = f2bf(b.z); v[7] = f2bf(b.w);
  *(short8*)(xb + i * 8) = v;
}

// ---------------------------------------------------------------------------
// Pass 3 (R3): 256x256x64 GEMM, 512 threads = 8 waves (2M x 4N), 8-phase.
// Per wave: 128x64 output = 8x4 frags of 16x16.
// LDS: lds[buf][A/B][256*64] bf16, XOR chunk-swizzled, 128 KiB total.
// Even K-tiles -> buf0, odd -> buf1 (fixed parity, NT even required).
// Stage plan per iteration (tiles t,t+1):
//   phi0..phi2: t+1 pairs 1..3 (buf1)  | phi3..phi6: t+2 pairs 0..3 (buf0)
//   phi7: t+3 pair 0 (buf1)            | vmcnt(2) at phi3 and phi7 only
// ---------------------------------------------------------------------------
#define GBM 256
#define GBN 256
#define GBK 64

__global__ __launch_bounds__(512, 2) void gemm256_kernel(
    const short* __restrict__ A, const short* __restrict__ Bt,
    const float* __restrict__ bias, float* __restrict__ C,
    int M, int N, int K) {
  __shared__ __align__(16) short lds[2][2][GBM * GBK];
  const int tid = threadIdx.x;
  const int nbx = N / GBN;
  const int nwg = gridDim.x;
  int bid = blockIdx.x;
  if ((nwg & 7) == 0) bid = (bid & 7) * (nwg >> 3) + (bid >> 3);  // T1
  const int bm = (bid / nbx) * GBM;
  const int bn = (bid % nbx) * GBN;

  const int wid = tid >> 6, lane = tid & 63;
  const int wr = wid >> 2, wc = wid & 3;  // 2x4 wave grid
  const int lrow = lane & 15;
  const int lkq = lane >> 4;

  const int NT = K / GBK;  // even (K % 128 == 0 guaranteed by launcher)

  // --- staging: pair = 2 global_load_lds (16B each, 1KB/wave each) ---
  auto stA = [&](int b, int kt, int r0) {
#pragma unroll
    for (int r = 0; r < 2; ++r) {
      const int c = (r0 + r) * 512 + tid;
      const int row = c >> 3;
      const int ch = (c & 7) ^ (row & 7);
      gload_lds16(A + (size_t)(bm + row) * K + kt + ch * 8,
                  (char*)&lds[b][0][0] + c * 16);
    }
  };
  auto stB = [&](int b, int kt, int r0) {
#pragma unroll
    for (int r = 0; r < 2; ++r) {
      const int c = (r0 + r) * 512 + tid;
      const int row = c >> 3;
      const int ch = (c & 7) ^ (row & 7);
      gload_lds16(Bt + (size_t)(bn + row) * K + kt + ch * 8,
                  (char*)&lds[b][1][0] + c * 16);
    }
  };

  short8 af[4][2], bf[4][2];
  f32x4 acc[8][4] = {};

  auto rdA = [&](const char* base, int ih) {  // A-half ih: rows ih*64..+63
#pragma unroll
    for (int i = 0; i < 4; ++i) {
      const int row = wr * 128 + ih * 64 + i * 16 + lrow;
#pragma unroll
      for (int kk = 0; kk < 2; ++kk) {
        const int q = (kk * 4 + lkq) ^ (row & 7);
        af[i][kk] = *(const short8*)(base + row * 128 + q * 16);
      }
    }
  };
  auto rdB = [&](const char* base, int jh) {  // B-cols jh*2, jh*2+1
#pragma unroll
    for (int j = 0; j < 2; ++j) {
      const int row = wc * 64 + (jh * 2 + j) * 16 + lrow;
#pragma unroll
      for (int kk = 0; kk < 2; ++kk) {
        const int q = (kk * 4 + lkq) ^ (row & 7);
        bf[jh * 2 + j][kk] = *(const short8*)(base + row * 128 + q * 16);
      }
    }
  };
  auto quad = [&](int ib, int jb) {  // 16 MFMA: frag rows ib..ib+3, cols jb,jb+1
    __builtin_amdgcn_s_setprio(1);
#pragma unroll
    for (int kk = 0; kk < 2; ++kk)
#pragma unroll
      for (int i = 0; i < 4; ++i)
#pragma unroll
        for (int j = 0; j < 2; ++j)
          acc[ib + i][jb + j] = __builtin_amdgcn_mfma_f32_16x16x32_bf16(
              af[i][kk], bf[jb + j][kk], acc[ib + i][jb + j], 0, 0, 0);
    __builtin_amdgcn_s_setprio(0);
  };

  const char* A0 = (const char*)&lds[0][0][0];
  const char* B0 = (const char*)&lds[0][1][0];
  const char* A1 = (const char*)&lds[1][0][0];
  const char* B1 = (const char*)&lds[1][1][0];

  // --- prologue: tile0 full (pairs 0-3), tile1 pair0; drain tile0 ---
  stA(0, 0, 0); stA(0, 0, 2); stB(0, 0, 0); stB(0, 0, 2);
  if (NT > 1) { stA(1, GBK, 0); wait_vm2(); } else { wait_vm0(); }
  bar();

  for (int t = 0; t < NT; t += 2) {
    const bool more = (t + 2 < NT);
    // phi0: tile t quad(mh0,nh0); stage t+1 pair1
    rdA(A0, 0); rdB(B0, 0);
    stA(1, (t + 1) * GBK, 2);
    phase_sync(); quad(0, 0); bar();
    // phi1: quad(mh0,nh1); stage t+1 pair2
    rdB(B0, 1);
    stB(1, (t + 1) * GBK, 0);
    phase_sync(); quad(0, 2); bar();
    // phi2: quad(mh1,nh0); stage t+1 pair3
    rdA(A0, 1);
    stB(1, (t + 1) * GBK, 2);
    phase_sync(); quad(4, 0); bar();
    // phi3: quad(mh1,nh1); stage t+2 pair0 into buf0 (reads drained by phi2);
    //       counted vmcnt -> tile t+1 fully in LDS after closing barrier
    if (more) { stA(0, (t + 2) * GBK, 0); wait_vm2(); } else { wait_vm0(); }
    phase_sync(); quad(4, 2); bar();
    // phi4: tile t+1 quad(mh0,nh0); stage t+2 pair1
    rdA(A1, 0); rdB(B1, 0);
    if (more) stA(0, (t + 2) * GBK, 2);
    phase_sync(); quad(0, 0); bar();
    // phi5: quad(mh0,nh1); stage t+2 pair2
    rdB(B1, 1);
    if (more) stB(0, (t + 2) * GBK, 0);
    phase_sync(); quad(0, 2); bar();
    // phi6: quad(mh1,nh0); stage t+2 pair3
    rdA(A1, 1);
    if (more) stB(0, (t + 2) * GBK, 2);
    phase_sync(); quad(4, 0); bar();
    // phi7: quad(mh1,nh1); stage t+3 pair0; counted vmcnt -> t+2 ready
    if (more) { stA(1, (t + 3) * GBK, 0); wait_vm2(); }
    phase_sync(); quad(4, 2); bar();
  }

  // --- epilogue: C = acc + bias. C/D map: col=lane&15, row=(lane>>4)*4+reg
  const int crow0 = bm + wr * 128 + (lane >> 4) * 4;
  const int ccol0 = bn + wc * 64 + (lane & 15);
#pragma unroll
  for (int j = 0; j < 4; ++j) {
    const float bv = bias[ccol0 + j * 16];
#pragma unroll
    for (int i = 0; i < 8; ++i) {
#pragma unroll
      for (int r = 0; r < 4; ++r) {
        C[(size_t)(crow0 + i * 16 + r) * N + ccol0 + j * 16] =
            acc[i][j][r] + bv;
      }
    }
  }
}

// ---------------------------------------------------------------------------
// 128x128x64 GEMM (fallback for non-256-divisible shapes).
// ---------------------------------------------------------------------------
#define BM 128
#define BN 128
#define BK 64

template <bool A_BF16>
__global__ __launch_bounds__(256) void gemm_bias_kernel(
    const void* __restrict__ Av, const short* __restrict__ Bt,
    const float* __restrict__ bias, float* __restrict__ C,
    int M, int N, int K) {
  __shared__ __align__(16) short As[BM * BK];
  __shared__ __align__(16) short Bs[BN * BK];
  const int tid = threadIdx.x;
  const int bm = blockIdx.y * BM;
  const int bn = blockIdx.x * BN;
  const int wid = tid >> 6, lane = tid & 63;
  const int wr = wid >> 1, wc = wid & 1;
  const int lrow = lane & 15;
  const int lk = (lane >> 4) * 8;

  f32x4 acc[4][4] = {};

  for (int kt = 0; kt < K; kt += BK) {
    if constexpr (A_BF16) {
      const short* A = (const short*)Av;
#pragma unroll
      for (int r = 0; r < 4; ++r) {
        const int c = r * 256 + tid;
        const int row = c >> 3, ch = c & 7;
        gload_lds16(A + (size_t)(bm + row) * K + kt + ch * 8,
                    (char*)As + c * 16);
      }
    } else {
      const float* A = (const float*)Av;
#pragma unroll
      for (int r = 0; r < 4; ++r) {
        const int c = r * 256 + tid;
        const int row = c >> 3, ch = c & 7;
        const float* src = A + (size_t)(bm + row) * K + kt + ch * 8;
        float4 f0 = *(const float4*)src;
        float4 f1 = *(const float4*)(src + 4);
        short8 v;
        v[0] = f2bf(f0.x); v[1] = f2bf(f0.y); v[2] = f2bf(f0.z); v[3] = f2bf(f0.w);
        v[4] = f2bf(f1.x); v[5] = f2bf(f1.y); v[6] = f2bf(f1.z); v[7] = f2bf(f1.w);
        *(short8*)((char*)As + c * 16) = v;
      }
    }
#pragma unroll
    for (int r = 0; r < 4; ++r) {
      const int c = r * 256 + tid;
      const int row = c >> 3, ch = c & 7;
      gload_lds16(Bt + (size_t)(bn + row) * K + kt + ch * 8,
                  (char*)Bs + c * 16);
    }
    __syncthreads();
#pragma unroll
    for (int kk = 0; kk < 2; ++kk) {
      short8 af[4], bf[4];
#pragma unroll
      for (int i = 0; i < 4; ++i)
        af[i] = *(const short8*)&As[(wr * 64 + i * 16 + lrow) * BK + kk * 32 + lk];
#pragma unroll
      for (int j = 0; j < 4; ++j)
        bf[j] = *(const short8*)&Bs[(wc * 64 + j * 16 + lrow) * BK + kk * 32 + lk];
#pragma unroll
      for (int i = 0; i < 4; ++i)
#pragma unroll
        for (int j = 0; j < 4; ++j)
          acc[i][j] = __builtin_amdgcn_mfma_f32_16x16x32_bf16(
              af[i], bf[j], acc[i][j], 0, 0, 0);
    }
    __syncthreads();
  }

  const int crow0 = bm + wr * 64 + (lane >> 4) * 4;
  const int ccol0 = bn + wc * 64 + (lane & 15);
#pragma unroll
  for (int j = 0; j < 4; ++j) {
    const float bv = bias[ccol0 + j * 16];
#pragma unroll
    for (int i = 0; i < 4; ++i) {
#pragma unroll
      for (int r = 0; r < 4; ++r) {
        C[(size_t)(crow0 + i * 16 + r) * N + ccol0 + j * 16] = acc[i][j][r] + bv;
      }
    }
  }
}

// ---------------------------------------------------------------------------
// Last-resort fallback: naive fused dequant GEMM.
// ---------------------------------------------------------------------------
__global__ __launch_bounds__(256) void naive_kernel(
    const float* __restrict__ x, const float* __restrict__ scales,
    const float* __restrict__ bias, const int* __restrict__ qw,
    const int* __restrict__ qz, float* __restrict__ out,
    int M, int K, int N) {
  long idx = (long)blockIdx.x * blockDim.x + threadIdx.x;
  if (idx >= (long)M * N) return;
  const int n = (int)(idx % N);
  const int m = (int)(idx / N);
  float acc = 0.f;
  for (int g = 0; g < K / 128; ++g) {
    const float sc = scales[(size_t)g * N + n];
    const float zp =
        (float)(((qz[(size_t)g * (N >> 3) + (n >> 3)] >> ((n & 7) * 4)) & 15) + 1);
    const float zs = zp * sc;
    for (int kw = 0; kw < 16; ++kw) {
      const int w = qw[(size_t)(g * 16 + kw) * N + n];
      const float* xp = &x[(size_t)m * K + g * 128 + kw * 8];
#pragma unroll
      for (int e = 0; e < 8; ++e)
        acc += xp[e] * ((float)((w >> (4 * e)) & 15) * sc - zs);
    }
  }
  out[idx] = acc + bias[n];
}

// ---------------------------------------------------------------------------
extern "C" void kernel_launch(void* const* d_in, const int* in_sizes, int n_in,
                              void* d_out, int out_size, void* d_ws,
                              size_t ws_size, hipStream_t stream) {
  const float* x = (const float*)d_in[0];
  const float* scales = (const float*)d_in[1];
  const float* bias = (const float*)d_in[2];
  const int* qweight = (const int*)d_in[3];
  const int* qzeros = (const int*)d_in[4];
  float* out = (float*)d_out;

  const int out_f = in_sizes[2];            // 12288
  const int kwords = in_sizes[3] / out_f;   // 512
  const int in_f = kwords * 8;              // 4096
  const int tokens = in_sizes[0] / in_f;    // 8192
  const int M = tokens, K = in_f, N = out_f;

  const size_t wt_bytes = (size_t)K * N * sizeof(short);
  const size_t xb_bytes = (size_t)M * K * sizeof(short);

  const bool div128 = (M % BM == 0) && (N % BN == 0) && (K % BK == 0) &&
                      (K % 128 == 0) && (N % 64 == 0);
  const bool div256 = (M % GBM == 0) && (N % GBN == 0) && (K % 128 == 0) &&
                      (N % 64 == 0);

  if (div128 && ws_size >= wt_bytes + xb_bytes) {
    short* Wt = (short*)d_ws;
    short* xb = (short*)((char*)d_ws + wt_bytes);
    dequant_kernel<<<dim3(N / 64, K / 64), 256, 0, stream>>>(
        qweight, qzeros, scales, Wt, K, N);
    const long n8 = (long)M * K / 8;
    cvt_kernel<<<(int)((n8 + 255) / 256), 256, 0, stream>>>(x, xb, n8);
    if (div256) {
      gemm256_kernel<<<(M / GBM) * (N / GBN), 512, 0, stream>>>(
          xb, Wt, bias, out, M, N, K);
    } else {
      gemm_bias_kernel<true><<<dim3(N / BN, M / BM), 256, 0, stream>>>(
          xb, Wt, bias, out, M, N, K);
    }
  } else if (div128 && ws_size >= wt_bytes) {
    short* Wt = (short*)d_ws;
    dequant_kernel<<<dim3(N / 64, K / 64), 256, 0, stream>>>(
        qweight, qzeros, scales, Wt, K, N);
    gemm_bias_kernel<false><<<dim3(N / BN, M / BM), 256, 0, stream>>>(
        x, Wt, bias, out, M, N, K);
  } else {
    const long total = (long)M * N;
    naive_kernel<<<(int)((total + 255) / 256), 256, 0, stream>>>(
        x, scales, bias, qweight, qzeros, out, M, K, N);
  }
}

// Round 4
// 847.863 us; speedup vs baseline: 1.1519x; 1.1519x over previous
//
#include <hip/hip_runtime.h>
#include <hip/hip_bf16.h>

// ---------------------------------------------------------------------------
// WeightOnlyLinear: y = x @ dequant4(qweight, scales, qzeros) + bias
//   x (8192,4096) fp32 | scales (32,12288) | bias (12288) | qweight (512,12288)
//   qzeros (32,1536) | out (8192,12288) fp32
// R4: ring-of-4 K-half LDS slots (32KB each), 1 barrier + 1 counted vmcnt per
//     32-MFMA phase, stage->use distance 3 phases. T1 swizzle + T5 setprio.
// ---------------------------------------------------------------------------

typedef __attribute__((ext_vector_type(8))) short short8;
typedef __attribute__((ext_vector_type(4))) float f32x4;

__device__ __forceinline__ short f2bf(float f) {
  unsigned u = __float_as_uint(f);
  u += 0x7fffu + ((u >> 16) & 1u);
  return (short)(u >> 16);
}

__device__ __forceinline__ void gload_lds16(const void* g, void* l) {
  __builtin_amdgcn_global_load_lds(
      (const __attribute__((address_space(1))) void*)g,
      (__attribute__((address_space(3))) void*)l,
      16, 0, 0);
}

__device__ __forceinline__ void bar() {
  asm volatile("" ::: "memory");
  __builtin_amdgcn_s_barrier();
  asm volatile("" ::: "memory");
}
__device__ __forceinline__ void wait_vm8() {
  asm volatile("s_waitcnt vmcnt(8)" ::: "memory");
}
__device__ __forceinline__ void wait_vm4() {
  asm volatile("s_waitcnt vmcnt(4)" ::: "memory");
}
__device__ __forceinline__ void wait_vm0() {
  asm volatile("s_waitcnt vmcnt(0)" ::: "memory");
}

// ---------------------------------------------------------------------------
// Pass 1: dequant + transpose. qweight (K/8, N) int32 -> Wt (N, K) bf16.
// ---------------------------------------------------------------------------
__global__ __launch_bounds__(256) void dequant_kernel(
    const int* __restrict__ qweight, const int* __restrict__ qzeros,
    const float* __restrict__ scales, short* __restrict__ Wt,
    int in_f, int out_f) {
  __shared__ __align__(16) short T[64][72];
  const int n0 = blockIdx.x * 64;
  const int k0 = blockIdx.y * 64;
  const int t = threadIdx.x;
  const int nl = t & 63;
  const int kw = t >> 6;
  const int n = n0 + nl;
  const int g = k0 >> 7;
  const float sc = scales[(size_t)g * out_f + n];
  const int zpw = qzeros[(size_t)g * (out_f >> 3) + (n >> 3)];
  const float zp = (float)(((zpw >> ((n & 7) * 4)) & 15) + 1);
  const float zs = zp * sc;
#pragma unroll
  for (int rr = 0; rr < 2; ++rr) {
    const int kwi = kw + rr * 4;
    const int w = qweight[(size_t)((k0 >> 3) + kwi) * out_f + n];
    short8 v;
#pragma unroll
    for (int e = 0; e < 8; ++e) {
      float f = (float)((w >> (4 * e)) & 15) * sc - zs;
      v[e] = f2bf(f);
    }
    *(short8*)&T[nl][kwi * 8] = v;
  }
  __syncthreads();
#pragma unroll
  for (int rr = 0; rr < 2; ++rr) {
    const int c = rr * 256 + t;
    const int row = c >> 3, ch = c & 7;
    *(short8*)&Wt[(size_t)(n0 + row) * in_f + k0 + ch * 8] =
        *(const short8*)&T[row][ch * 8];
  }
}

// ---------------------------------------------------------------------------
// Pass 2: x fp32 -> bf16.
// ---------------------------------------------------------------------------
__global__ __launch_bounds__(256) void cvt_kernel(
    const float* __restrict__ x, short* __restrict__ xb, long n8) {
  long i = (long)blockIdx.x * blockDim.x + threadIdx.x;
  if (i >= n8) return;
  const float* src = x + i * 8;
  float4 a = *(const float4*)src;
  float4 b = *(const float4*)(src + 4);
  short8 v;
  v[0] = f2bf(a.x); v[1] = f2bf(a.y); v[2] = f2bf(a.z); v[3] = f2bf(a.w);
  v[4] = f2bf(b.x); v[5] = f2bf(b.y); v[6] = f2bf(b.z); v[7] = f2bf(b.w);
  *(short8*)(xb + i * 8) = v;
}

// ---------------------------------------------------------------------------
// Pass 3 (R4): 256x256 GEMM, 512 threads = 8 waves (2M x 4N).
// LDS ring: 4 slots x 32KB. Slot = K-half h: A[256 rows][32 k] at byte 0,
// B[256 rows][32 k] at byte 16384. Chunk (row, q) [q = k-quarter 0..3,
// 16B each] stored at byte row*64 + (q ^ ((row>>1)&3))*16  (bank-spread,
// bijective per row; stage sources the inverse permutation -> rule 21 ok).
//
// Phase p (one K-half, P = K/32 phases):
//   vmcnt(8)  [own stage loads of K-half p, issued at phase p-3, landed]
//   s_barrier [all waves confirmed -> slot p&3 fully populated; also proves
//              all waves' phase p-1 ds_reads retired -> slot (p+3)&3 free]
//   12x ds_read_b128 (bf[4], af[4] mh0; af mh1 reloaded mid-phase)
//   stage K-half p+3 -> slot (p+3)&3   [4x global_load_lds]
//   32 MFMA (2 setprio clusters of 16)
// Tail ledger (P-3/P-2/P-1 stage nothing): outstanding 12->vm8, 8->vm4, 4->vm0.
// ---------------------------------------------------------------------------
#define GBM 256
#define GBN 256

__global__ __launch_bounds__(512, 2) void gemm256_kernel(
    const short* __restrict__ A, const short* __restrict__ Bt,
    const float* __restrict__ bias, float* __restrict__ C,
    int M, int N, int K) {
  __shared__ __align__(16) char lds[4][32768];
  const int tid = threadIdx.x;
  const int nbx = N / GBN;
  const int nwg = gridDim.x;
  int bid = blockIdx.x;
  if ((nwg & 7) == 0) bid = (bid & 7) * (nwg >> 3) + (bid >> 3);  // T1
  const int bm = (bid / nbx) * GBM;
  const int bn = (bid % nbx) * GBN;

  const int wid = tid >> 6, lane = tid & 63;
  const int wr = wid >> 2, wc = wid & 3;  // 2x4 wave grid
  const int lrow = lane & 15;
  const int lq = lane >> 4;  // k-quarter within the 32-k half

  const int P = K >> 5;  // number of K-halves (phases); P >= 4, even

  // --- ds_read byte offsets within a slot (thread-invariant) ---
  int offA[2][4], offB[4];
#pragma unroll
  for (int mh = 0; mh < 2; ++mh)
#pragma unroll
    for (int i = 0; i < 4; ++i) {
      const int row = wr * 128 + mh * 64 + i * 16 + lrow;
      const int s = lq ^ ((row >> 1) & 3);
      offA[mh][i] = row * 64 + s * 16;
    }
#pragma unroll
  for (int j = 0; j < 4; ++j) {
    const int row = wc * 64 + j * 16 + lrow;
    const int s = lq ^ ((row >> 1) & 3);
    offB[j] = 16384 + row * 64 + s * 16;
  }

  // --- stage addressing (thread-invariant): chunks c = tid, tid+512 ---
  const int c0 = tid, c1 = tid + 512;
  const int rA0 = c0 >> 2, qA0 = (c0 & 3) ^ ((rA0 >> 1) & 3);
  const int rA1 = c1 >> 2, qA1 = (c1 & 3) ^ ((rA1 >> 1) & 3);
  const short* srcA0 = A + (size_t)(bm + rA0) * K + qA0 * 8;
  const short* srcA1 = A + (size_t)(bm + rA1) * K + qA1 * 8;
  const short* srcB0 = Bt + (size_t)(bn + rA0) * K + qA0 * 8;
  const short* srcB1 = Bt + (size_t)(bn + rA1) * K + qA1 * 8;
  const int dA0 = c0 * 16, dA1 = c1 * 16;
  const int dB0 = 16384 + c0 * 16, dB1 = 16384 + c1 * 16;

  auto STAGE = [&](int slot, int h) {
    const int kof = h * 32;
    char* sb = &lds[slot][0];
    gload_lds16(srcA0 + kof, sb + dA0);
    gload_lds16(srcA1 + kof, sb + dA1);
    gload_lds16(srcB0 + kof, sb + dB0);
    gload_lds16(srcB1 + kof, sb + dB1);
  };

  f32x4 acc[8][4] = {};

  auto PHASE = [&](int p, bool doStage) {
    const char* sb = &lds[p & 3][0];
    short8 bf[4], af[4];
#pragma unroll
    for (int j = 0; j < 4; ++j) bf[j] = *(const short8*)(sb + offB[j]);
#pragma unroll
    for (int i = 0; i < 4; ++i) af[i] = *(const short8*)(sb + offA[0][i]);
    if (doStage) STAGE((p + 3) & 3, p + 3);
    __builtin_amdgcn_s_setprio(1);
#pragma unroll
    for (int i = 0; i < 4; ++i)
#pragma unroll
      for (int j = 0; j < 4; ++j)
        acc[i][j] = __builtin_amdgcn_mfma_f32_16x16x32_bf16(
            af[i], bf[j], acc[i][j], 0, 0, 0);
    __builtin_amdgcn_s_setprio(0);
    short8 af2[4];
#pragma unroll
    for (int i = 0; i < 4; ++i) af2[i] = *(const short8*)(sb + offA[1][i]);
    __builtin_amdgcn_s_setprio(1);
#pragma unroll
    for (int i = 0; i < 4; ++i)
#pragma unroll
      for (int j = 0; j < 4; ++j)
        acc[4 + i][j] = __builtin_amdgcn_mfma_f32_16x16x32_bf16(
            af2[i], bf[j], acc[4 + i][j], 0, 0, 0);
    __builtin_amdgcn_s_setprio(0);
  };

  // --- prologue: stage K-halves 0,1,2 into slots 0,1,2 (12 loads) ---
  STAGE(0, 0);
  STAGE(1, 1);
  STAGE(2, 2);

  // --- main loop: phases 0 .. P-4 (stage h=p+3 valid) ---
  for (int p = 0; p <= P - 4; ++p) {
    wait_vm8();
    bar();
    PHASE(p, true);
  }
  // --- tail: phases P-3, P-2, P-1 (no stage; drain ring) ---
  wait_vm8(); bar(); PHASE(P - 3, false);
  wait_vm4(); bar(); PHASE(P - 2, false);
  wait_vm0(); bar(); PHASE(P - 1, false);

  // --- epilogue: C = acc + bias. C/D map: col=lane&15, row=(lane>>4)*4+reg
  const int crow0 = bm + wr * 128 + (lane >> 4) * 4;
  const int ccol0 = bn + wc * 64 + (lane & 15);
#pragma unroll
  for (int j = 0; j < 4; ++j) {
    const float bv = bias[ccol0 + j * 16];
#pragma unroll
    for (int i = 0; i < 8; ++i) {
#pragma unroll
      for (int r = 0; r < 4; ++r) {
        C[(size_t)(crow0 + i * 16 + r) * N + ccol0 + j * 16] =
            acc[i][j][r] + bv;
      }
    }
  }
}

// ---------------------------------------------------------------------------
// 128x128x64 GEMM (fallback for non-256-divisible shapes).
// ---------------------------------------------------------------------------
#define BM 128
#define BN 128
#define BK 64

template <bool A_BF16>
__global__ __launch_bounds__(256) void gemm_bias_kernel(
    const void* __restrict__ Av, const short* __restrict__ Bt,
    const float* __restrict__ bias, float* __restrict__ C,
    int M, int N, int K) {
  __shared__ __align__(16) short As[BM * BK];
  __shared__ __align__(16) short Bs[BN * BK];
  const int tid = threadIdx.x;
  const int bm = blockIdx.y * BM;
  const int bn = blockIdx.x * BN;
  const int wid = tid >> 6, lane = tid & 63;
  const int wr = wid >> 1, wc = wid & 1;
  const int lrow = lane & 15;
  const int lk = (lane >> 4) * 8;

  f32x4 acc[4][4] = {};

  for (int kt = 0; kt < K; kt += BK) {
    if constexpr (A_BF16) {
      const short* A = (const short*)Av;
#pragma unroll
      for (int r = 0; r < 4; ++r) {
        const int c = r * 256 + tid;
        const int row = c >> 3, ch = c & 7;
        gload_lds16(A + (size_t)(bm + row) * K + kt + ch * 8,
                    (char*)As + c * 16);
      }
    } else {
      const float* A = (const float*)Av;
#pragma unroll
      for (int r = 0; r < 4; ++r) {
        const int c = r * 256 + tid;
        const int row = c >> 3, ch = c & 7;
        const float* src = A + (size_t)(bm + row) * K + kt + ch * 8;
        float4 f0 = *(const float4*)src;
        float4 f1 = *(const float4*)(src + 4);
        short8 v;
        v[0] = f2bf(f0.x); v[1] = f2bf(f0.y); v[2] = f2bf(f0.z); v[3] = f2bf(f0.w);
        v[4] = f2bf(f1.x); v[5] = f2bf(f1.y); v[6] = f2bf(f1.z); v[7] = f2bf(f1.w);
        *(short8*)((char*)As + c * 16) = v;
      }
    }
#pragma unroll
    for (int r = 0; r < 4; ++r) {
      const int c = r * 256 + tid;
      const int row = c >> 3, ch = c & 7;
      gload_lds16(Bt + (size_t)(bn + row) * K + kt + ch * 8,
                  (char*)Bs + c * 16);
    }
    __syncthreads();
#pragma unroll
    for (int kk = 0; kk < 2; ++kk) {
      short8 af[4], bf[4];
#pragma unroll
      for (int i = 0; i < 4; ++i)
        af[i] = *(const short8*)&As[(wr * 64 + i * 16 + lrow) * BK + kk * 32 + lk];
#pragma unroll
      for (int j = 0; j < 4; ++j)
        bf[j] = *(const short8*)&Bs[(wc * 64 + j * 16 + lrow) * BK + kk * 32 + lk];
#pragma unroll
      for (int i = 0; i < 4; ++i)
#pragma unroll
        for (int j = 0; j < 4; ++j)
          acc[i][j] = __builtin_amdgcn_mfma_f32_16x16x32_bf16(
              af[i], bf[j], acc[i][j], 0, 0, 0);
    }
    __syncthreads();
  }

  const int crow0 = bm + wr * 64 + (lane >> 4) * 4;
  const int ccol0 = bn + wc * 64 + (lane & 15);
#pragma unroll
  for (int j = 0; j < 4; ++j) {
    const float bv = bias[ccol0 + j * 16];
#pragma unroll
    for (int i = 0; i < 4; ++i) {
#pragma unroll
      for (int r = 0; r < 4; ++r) {
        C[(size_t)(crow0 + i * 16 + r) * N + ccol0 + j * 16] = acc[i][j][r] + bv;
      }
    }
  }
}

// ---------------------------------------------------------------------------
// Last-resort fallback: naive fused dequant GEMM.
// ---------------------------------------------------------------------------
__global__ __launch_bounds__(256) void naive_kernel(
    const float* __restrict__ x, const float* __restrict__ scales,
    const float* __restrict__ bias, const int* __restrict__ qw,
    const int* __restrict__ qz, float* __restrict__ out,
    int M, int K, int N) {
  long idx = (long)blockIdx.x * blockDim.x + threadIdx.x;
  if (idx >= (long)M * N) return;
  const int n = (int)(idx % N);
  const int m = (int)(idx / N);
  float acc = 0.f;
  for (int g = 0; g < K / 128; ++g) {
    const float sc = scales[(size_t)g * N + n];
    const float zp =
        (float)(((qz[(size_t)g * (N >> 3) + (n >> 3)] >> ((n & 7) * 4)) & 15) + 1);
    const float zs = zp * sc;
    for (int kw = 0; kw < 16; ++kw) {
      const int w = qw[(size_t)(g * 16 + kw) * N + n];
      const float* xp = &x[(size_t)m * K + g * 128 + kw * 8];
#pragma unroll
      for (int e = 0; e < 8; ++e)
        acc += xp[e] * ((float)((w >> (4 * e)) & 15) * sc - zs);
    }
  }
  out[idx] = acc + bias[n];
}

// ---------------------------------------------------------------------------
extern "C" void kernel_launch(void* const* d_in, const int* in_sizes, int n_in,
                              void* d_out, int out_size, void* d_ws,
                              size_t ws_size, hipStream_t stream) {
  const float* x = (const float*)d_in[0];
  const float* scales = (const float*)d_in[1];
  const float* bias = (const float*)d_in[2];
  const int* qweight = (const int*)d_in[3];
  const int* qzeros = (const int*)d_in[4];
  float* out = (float*)d_out;

  const int out_f = in_sizes[2];            // 12288
  const int kwords = in_sizes[3] / out_f;   // 512
  const int in_f = kwords * 8;              // 4096
  const int tokens = in_sizes[0] / in_f;    // 8192
  const int M = tokens, K = in_f, N = out_f;

  const size_t wt_bytes = (size_t)K * N * sizeof(short);
  const size_t xb_bytes = (size_t)M * K * sizeof(short);

  const bool div128 = (M % BM == 0) && (N % BN == 0) && (K % BK == 0) &&
                      (K % 128 == 0) && (N % 64 == 0);
  const bool div256 = (M % GBM == 0) && (N % GBN == 0) && (K % 128 == 0) &&
                      (N % 64 == 0);

  if (div128 && ws_size >= wt_bytes + xb_bytes) {
    short* Wt = (short*)d_ws;
    short* xb = (short*)((char*)d_ws + wt_bytes);
    dequant_kernel<<<dim3(N / 64, K / 64), 256, 0, stream>>>(
        qweight, qzeros, scales, Wt, K, N);
    const long n8 = (long)M * K / 8;
    cvt_kernel<<<(int)((n8 + 255) / 256), 256, 0, stream>>>(x, xb, n8);
    if (div256) {
      gemm256_kernel<<<(M / GBM) * (N / GBN), 512, 0, stream>>>(
          xb, Wt, bias, out, M, N, K);
    } else {
      gemm_bias_kernel<true><<<dim3(N / BN, M / BM), 256, 0, stream>>>(
          xb, Wt, bias, out, M, N, K);
    }
  } else if (div128 && ws_size >= wt_bytes) {
    short* Wt = (short*)d_ws;
    dequant_kernel<<<dim3(N / 64, K / 64), 256, 0, stream>>>(
        qweight, qzeros, scales, Wt, K, N);
    gemm_bias_kernel<false><<<dim3(N / BN, M / BM), 256, 0, stream>>>(
        x, Wt, bias, out, M, N, K);
  } else {
    const long total = (long)M * N;
    naive_kernel<<<(int)((total + 255) / 256), 256, 0, stream>>>(
        x, scales, bias, qweight, qzeros, out, M, K, N);
  }
}